// Round 4
// baseline (1826.953 us; speedup 1.0000x reference)
//
#include <hip/hip_runtime.h>
#include <math.h>

// Problem constants
#define NBOX 512
#define BATCH 16
#define TT 32
#define FEAT 2048
#define NCLS 80
#define CTXD 1024
#define FCD 1024
#define HID 1024
#define IN_DIM 3152     // FEAT + NCLS + CTXD
#define G4 4096         // 4*HID

// ---------------------------------------------------------------------------
// Kernel 1: build x = concat([box_feats, boxes_ext[:,5:], ctx_rep], dim=1)
// ---------------------------------------------------------------------------
__global__ void build_x(const float* __restrict__ boxes_ext,
                        const float* __restrict__ box_feats,
                        const float* __restrict__ spatial_ctx,
                        const int* __restrict__ box_im_ids,
                        float* __restrict__ x)
{
    int idx = blockIdx.x * blockDim.x + threadIdx.x;
    const int total = NBOX * IN_DIM;
    for (; idx < total; idx += gridDim.x * blockDim.x) {
        int n = idx / IN_DIM;
        int k = idx - n * IN_DIM;
        float v;
        if (k < FEAT) {
            v = box_feats[n * FEAT + k];
        } else if (k < FEAT + NCLS) {
            v = boxes_ext[n * 85 + 5 + (k - FEAT)];
        } else {
            v = spatial_ctx[box_im_ids[n] * CTXD + (k - FEAT - NCLS)];
        }
        x[idx] = v;
    }
}

// ---------------------------------------------------------------------------
// Kernel 2: emb GEMM, K-split partials. 64x64 tile, 256 threads (4 waves),
// 4x4 micro-tile, BK=16 -> 16 waves/CU occupancy (fix for the 10% occ).
// Grid (8,16,8). K chunks 400/352, both %16==0.
// ---------------------------------------------------------------------------
__global__ __launch_bounds__(256) void gemm_emb_p2(
    const float* __restrict__ A,   // x [512][3152]
    const float* __restrict__ Bm,  // w_fc [1024][3152]
    float* __restrict__ part)      // [8][512][1024]
{
    __shared__ float As[16][68];
    __shared__ float Bs[16][68];
    const int bm = blockIdx.x * 64;
    const int bn = blockIdx.y * 64;
    const int kz = blockIdx.z;
    const int kbeg = kz * 400;
    const int kend = (kz == 7) ? IN_DIM : (kbeg + 400);
    const int t = threadIdx.x;
    const int tx = t & 15;         // 0..15 col-quad
    const int ty = t >> 4;         // 0..15 row-quad
    const int lr = t >> 2;         // staging row 0..63
    const int lk = (t & 3) * 4;    // staging k offset
    float acc[4][4] = {};

    const float* ap = A  + (size_t)(bm + lr) * IN_DIM + kbeg + lk;
    const float* bp = Bm + (size_t)(bn + lr) * IN_DIM + kbeg + lk;
    float4 pa = *(const float4*)ap;
    float4 pb = *(const float4*)bp;

    for (int k0 = kbeg; k0 < kend; k0 += 16) {
        As[lk+0][lr] = pa.x; As[lk+1][lr] = pa.y; As[lk+2][lr] = pa.z; As[lk+3][lr] = pa.w;
        Bs[lk+0][lr] = pb.x; Bs[lk+1][lr] = pb.y; Bs[lk+2][lr] = pb.z; Bs[lk+3][lr] = pb.w;
        __syncthreads();
        if (k0 + 16 < kend) {
            pa = *(const float4*)(ap + (k0 + 16 - kbeg));
            pb = *(const float4*)(bp + (k0 + 16 - kbeg));
        }
#pragma unroll
        for (int k = 0; k < 16; ++k) {
            float4 a4 = *(const float4*)&As[k][ty * 4];
            float4 b4 = *(const float4*)&Bs[k][tx * 4];
            float av[4] = {a4.x, a4.y, a4.z, a4.w};
            float bv[4] = {b4.x, b4.y, b4.z, b4.w};
#pragma unroll
            for (int i = 0; i < 4; ++i)
#pragma unroll
                for (int j = 0; j < 4; ++j)
                    acc[i][j] = fmaf(av[i], bv[j], acc[i][j]);
        }
        __syncthreads();
    }
    float* Cp = part + (size_t)kz * (NBOX * FCD) + (size_t)(bm + ty * 4) * FCD + bn + tx * 4;
#pragma unroll
    for (int i = 0; i < 4; ++i) {
        float4 v = make_float4(acc[i][0], acc[i][1], acc[i][2], acc[i][3]);
        *(float4*)(Cp + (size_t)i * FCD) = v;
    }
}

// Reduce K-split partials + bias + relu -> emb (written into d_out region)
__global__ void reduce_emb(const float* __restrict__ part,
                           const float* __restrict__ bias,
                           float* __restrict__ emb)
{
    int i = blockIdx.x * blockDim.x + threadIdx.x;
    if (i >= NBOX * FCD) return;
    float s = 0.f;
#pragma unroll
    for (int z = 0; z < 8; ++z) s += part[(size_t)z * (NBOX * FCD) + i];
    s += bias[i & (FCD - 1)];
    emb[i] = fmaxf(s, 0.f);
}

// ---------------------------------------------------------------------------
// Kernel 3: xg = emb @ w_ih^T + b_ih + b_hh (both dirs), same 256-thr tile.
// Grid (8, 128): by>>6 = dir, (by&63)*64 = col tile. K = 1024.
// ---------------------------------------------------------------------------
__global__ __launch_bounds__(256) void gemm_xg_p2(
    const float* __restrict__ A,   // emb [512][1024]
    const float* __restrict__ Bf, const float* __restrict__ Br,
    const float* __restrict__ bif, const float* __restrict__ bhf,
    const float* __restrict__ bir, const float* __restrict__ bhr,
    float* __restrict__ xg)        // [2][512][4096]
{
    __shared__ float As[16][68];
    __shared__ float Bs[16][68];
    const int bm = blockIdx.x * 64;
    const int by = blockIdx.y;
    const int dir = by >> 6;
    const int bn = (by & 63) * 64;
    const float* Bm = dir ? Br : Bf;
    const float* b1 = dir ? bir : bif;
    const float* b2 = dir ? bhr : bhf;
    float* C = xg + ((size_t)dir << 21);
    const int t = threadIdx.x;
    const int tx = t & 15;
    const int ty = t >> 4;
    const int lr = t >> 2;
    const int lk = (t & 3) * 4;
    float acc[4][4] = {};

    const float* ap = A  + (size_t)(bm + lr) * FCD + lk;
    const float* bp = Bm + (size_t)(bn + lr) * FCD + lk;
    float4 pa = *(const float4*)ap;
    float4 pb = *(const float4*)bp;

    for (int k0 = 0; k0 < 1024; k0 += 16) {
        As[lk+0][lr] = pa.x; As[lk+1][lr] = pa.y; As[lk+2][lr] = pa.z; As[lk+3][lr] = pa.w;
        Bs[lk+0][lr] = pb.x; Bs[lk+1][lr] = pb.y; Bs[lk+2][lr] = pb.z; Bs[lk+3][lr] = pb.w;
        __syncthreads();
        if (k0 + 16 < 1024) {
            pa = *(const float4*)(ap + k0 + 16);
            pb = *(const float4*)(bp + k0 + 16);
        }
#pragma unroll
        for (int k = 0; k < 16; ++k) {
            float4 a4 = *(const float4*)&As[k][ty * 4];
            float4 b4 = *(const float4*)&Bs[k][tx * 4];
            float av[4] = {a4.x, a4.y, a4.z, a4.w};
            float bv[4] = {b4.x, b4.y, b4.z, b4.w};
#pragma unroll
            for (int i = 0; i < 4; ++i)
#pragma unroll
                for (int j = 0; j < 4; ++j)
                    acc[i][j] = fmaf(av[i], bv[j], acc[i][j]);
        }
        __syncthreads();
    }
    const int col = bn + tx * 4;
    float4 b1v = *(const float4*)&b1[col];
    float4 b2v = *(const float4*)&b2[col];
#pragma unroll
    for (int i = 0; i < 4; ++i) {
        float4 v;
        v.x = acc[i][0] + b1v.x + b2v.x;
        v.y = acc[i][1] + b1v.y + b2v.y;
        v.z = acc[i][2] + b1v.z + b2v.z;
        v.w = acc[i][3] + b1v.w + b2v.w;
        *(float4*)(C + (size_t)(bm + ty * 4 + i) * G4 + col) = v;
    }
}

// ---------------------------------------------------------------------------
// Kernel 4: PERSISTENT bidirectional LSTM. 256 blocks x 512 threads,
// 1 block/CU (forced by 128 KB dynamic LDS) -> co-resident -> grid barrier OK.
// Block (dir = blk>>7, hb = (blk&127)*8) owns 8 hidden units x 4 gates = 32
// gate-cols. Weights (32 x 1024 fp32 = 128 KB) loaded ONCE into XOR-swizzled
// LDS [k][32]. Per step: per-wave 8col x 8batch outer-product, lane = k-slice
// {i*64+lane}, shuffle-halving reduction, gates/c/h/hsum in registers.
// One device-scope barrier per step (per-step counters, pre-zeroed).
// ---------------------------------------------------------------------------
__global__ __launch_bounds__(512, 2) void lstm_persist(
    const float* __restrict__ whh_f, const float* __restrict__ whh_r,
    const float* __restrict__ xg,    // [2][512][4096]
    float* __restrict__ h_buf,       // [2 phases][2 dirs][1024][16]
    unsigned* __restrict__ ctr,      // [32] zeroed
    float* __restrict__ out)         // object_context [16][2048]
{
    extern __shared__ char smem[];   // 128 KB swizzled weights
    const int blk = blockIdx.x;
    const int dir = blk >> 7;
    const int hb  = (blk & 127) * 8;
    const int t   = threadIdx.x;
    const int lane = t & 63;
    const int wv   = t >> 6;        // wave 0..7
    const int jp   = wv >> 1;       // j-pair 0..3
    const int bg   = wv & 1;        // batch half

    // ---- one-time: load w_hh rows (gate-col = g*1024 + hb + jlg) into LDS
    {
        const float* wsrc = dir ? whh_r : whh_f;
        const int c  = t >> 4;          // block-local col 0..31 (c = jlg*4+g)
        const int kq = t & 15;          // 64-k chunk
        const int row = (c & 3) * 1024 + hb + (c >> 2);
        const float* src = wsrc + (size_t)row * 1024 + kq * 64;
#pragma unroll 4
        for (int m = 0; m < 16; ++m) {
            float4 v = *(const float4*)(src + m * 4);
            int k0 = kq * 64 + m * 4;
            float vv[4] = {v.x, v.y, v.z, v.w};
#pragma unroll
            for (int j = 0; j < 4; ++j) {
                int k = k0 + j;
                int addr = ((k << 7) | (c << 2)) ^ ((k & 7) << 4);
                *(float*)(smem + addr) = vv[j];
            }
        }
    }
    __syncthreads();

    const float* xgd = xg + ((size_t)dir << 21);
    const int jl = lane >> 5;          // 0/1 within pair
    const int gg = (lane >> 3) & 3;    // gate id; g==0 lanes own epilogue
    const int bb = lane & 7;
    const int j  = hb + jp * 2 + jl;   // global hidden index
    const int b  = bg * 8 + bb;        // batch

    float c_st = 0.f, hsum = 0.f;

#pragma unroll 1
    for (int s = 0; s < TT; ++s) {
        const float* hrd = h_buf + (s & 1) * 32768 + dir * 16384;
        float* hwr = h_buf + ((s + 1) & 1) * 32768 + dir * 16384;
        const int tstep = dir ? (31 - s) : s;
        const int n = b * 32 + tstep;
        // xg prefetch (gate order i,f,g,o at col g*1024 + j)
        const float* xp = xgd + (size_t)n * G4 + j;
        float x0 = xp[0], x1 = xp[1024], x2 = xp[2048], x3 = xp[3072];

        float acc[64];
#pragma unroll
        for (int a = 0; a < 64; ++a) acc[a] = 0.f;

        // prime h loads for first 8 k-iterations (coalesced: k = i*64+lane)
        float4 hb0[8], hb1[8];
#pragma unroll
        for (int i = 0; i < 8; ++i) {
            const float4* hp = (const float4*)(hrd + (i * 64 + lane) * 16 + bg * 8);
            hb0[i] = hp[0]; hb1[i] = hp[1];
        }
#pragma unroll
        for (int i = 0; i < 16; ++i) {
            const int k = i * 64 + lane;
            const int aw = ((k << 7) | (jp << 5)) ^ ((lane & 7) << 4);
            float4 w0 = *(const float4*)(smem + aw);
            float4 w1 = *(const float4*)(smem + (aw ^ 16));
            float4 h0 = hb0[i & 7], h1 = hb1[i & 7];
            if (i < 8) {   // rolling prefetch of iterations 8..15
                const float4* hp = (const float4*)(hrd + ((i + 8) * 64 + lane) * 16 + bg * 8);
                hb0[i & 7] = hp[0]; hb1[i & 7] = hp[1];
            }
            float wr[8] = {w0.x, w0.y, w0.z, w0.w, w1.x, w1.y, w1.z, w1.w};
            float hr[8] = {h0.x, h0.y, h0.z, h0.w, h1.x, h1.y, h1.z, h1.w};
#pragma unroll
            for (int cc = 0; cc < 8; ++cc)
#pragma unroll
                for (int b2 = 0; b2 < 8; ++b2)
                    acc[cc * 8 + b2] = fmaf(wr[cc], hr[b2], acc[cc * 8 + b2]);
        }

        // ---- shuffle-halving reduction across 64 k-slice lanes.
        // MSB-first; after all stages lane L holds slot L = (cc = L>>3, bb = L&7).
#pragma unroll
        for (int i2 = 0; i2 < 32; ++i2) {
            float ka = acc[i2], kb = acc[i2 + 32];
            float ta = __shfl_xor(ka, 32), tb = __shfl_xor(kb, 32);
            acc[i2] = (lane & 32) ? (kb + tb) : (ka + ta);
        }
#pragma unroll
        for (int i2 = 0; i2 < 16; ++i2) {
            float ka = acc[i2], kb = acc[i2 + 16];
            float ta = __shfl_xor(ka, 16), tb = __shfl_xor(kb, 16);
            acc[i2] = (lane & 16) ? (kb + tb) : (ka + ta);
        }
#pragma unroll
        for (int i2 = 0; i2 < 8; ++i2) {
            float ka = acc[i2], kb = acc[i2 + 8];
            float ta = __shfl_xor(ka, 8), tb = __shfl_xor(kb, 8);
            acc[i2] = (lane & 8) ? (kb + tb) : (ka + ta);
        }
#pragma unroll
        for (int i2 = 0; i2 < 4; ++i2) {
            float ka = acc[i2], kb = acc[i2 + 4];
            float ta = __shfl_xor(ka, 4), tb = __shfl_xor(kb, 4);
            acc[i2] = (lane & 4) ? (kb + tb) : (ka + ta);
        }
#pragma unroll
        for (int i2 = 0; i2 < 2; ++i2) {
            float ka = acc[i2], kb = acc[i2 + 2];
            float ta = __shfl_xor(ka, 2), tb = __shfl_xor(kb, 2);
            acc[i2] = (lane & 2) ? (kb + tb) : (ka + ta);
        }
        {
            float ka = acc[0], kb = acc[1];
            float ta = __shfl_xor(ka, 1), tb = __shfl_xor(kb, 1);
            acc[0] = (lane & 1) ? (kb + tb) : (ka + ta);
        }
        // gate gather: lane (g=0) pulls f/g/o from lanes +8/+16/+24
        float gv = acc[0];
        float fv = __shfl_xor(gv, 8);
        float gv2 = __shfl_xor(gv, 16);
        float ov = __shfl_xor(gv, 24);

        if (gg == 0) {
            float pi = gv + x0, pf = fv + x1, pg = gv2 + x2, po = ov + x3;
            float si = 1.f / (1.f + __expf(-pi));
            float sf = 1.f / (1.f + __expf(-pf));
            float so = 1.f / (1.f + __expf(-po));
            c_st = sf * c_st + si * tanhf(pg);
            float hn = so * tanhf(c_st);
            hsum += hn;
            hwr[j * 16 + b] = hn;
        }

        if (s != TT - 1) {
            __threadfence();               // publish h writes device-wide
            __syncthreads();
            if (t == 0) {
                __hip_atomic_fetch_add(&ctr[s], 1u, __ATOMIC_ACQ_REL, __HIP_MEMORY_SCOPE_AGENT);
                while (__hip_atomic_load(&ctr[s], __ATOMIC_ACQUIRE, __HIP_MEMORY_SCOPE_AGENT) < 256u)
                    __builtin_amdgcn_s_sleep(2);
            }
            __syncthreads();
        }
    }
    if (gg == 0)
        out[b * 2048 + dir * 1024 + j] = hsum * (1.0f / TT);
}

// ---------------------------------------------------------------------------
// Workspace (floats), total ~40.3 MB:
//   x     @ 0          (1,613,824)
//   part  @ 1,613,824  (4,194,304)
//   xg    @ 5,808,128  (4,194,304)
//   h_buf @ 10,002,432 (2 phases x 2 dirs x 1024 x 16 = 65,536)
//   ctr   @ 10,067,968 (32 u32)
// ---------------------------------------------------------------------------
extern "C" void kernel_launch(void* const* d_in, const int* in_sizes, int n_in,
                              void* d_out, int out_size, void* d_ws, size_t ws_size,
                              hipStream_t stream)
{
    const float* boxes_ext   = (const float*)d_in[0];
    const float* box_feats   = (const float*)d_in[1];
    const float* spatial_ctx = (const float*)d_in[2];
    const int*   box_im_ids  = (const int*)d_in[4];
    const float* w_fc   = (const float*)d_in[5];
    const float* b_fc   = (const float*)d_in[6];
    const float* w_ih_f = (const float*)d_in[7];
    const float* w_hh_f = (const float*)d_in[8];
    const float* b_ih_f = (const float*)d_in[9];
    const float* b_hh_f = (const float*)d_in[10];
    const float* w_ih_r = (const float*)d_in[11];
    const float* w_hh_r = (const float*)d_in[12];
    const float* b_ih_r = (const float*)d_in[13];
    const float* b_hh_r = (const float*)d_in[14];

    float* ws    = (float*)d_ws;
    float* x     = ws;
    float* part  = ws + 1613824;
    float* xg    = ws + 5808128;
    float* h_buf = ws + 10002432;
    unsigned* ctr = (unsigned*)(ws + 10067968);

    float* out = (float*)d_out;
    float* emb = out + 32768;   // second output region, also LSTM input

    (void)hipFuncSetAttribute((const void*)lstm_persist,
                              hipFuncAttributeMaxDynamicSharedMemorySize, 131072);

    hipMemsetAsync(h_buf, 0, 131072, stream);   // phase-0 h for both dirs
    hipMemsetAsync(ctr, 0, 128, stream);        // 32 barrier counters

    build_x<<<2048, 256, 0, stream>>>(boxes_ext, box_feats, spatial_ctx, box_im_ids, x);
    gemm_emb_p2<<<dim3(8, 16, 8), 256, 0, stream>>>(x, w_fc, part);
    reduce_emb<<<2048, 256, 0, stream>>>(part, b_fc, emb);
    gemm_xg_p2<<<dim3(8, 128), 256, 0, stream>>>(emb, w_ih_f, w_ih_r,
                                                 b_ih_f, b_hh_f, b_ih_r, b_hh_r, xg);
    lstm_persist<<<256, 512, 131072, stream>>>(w_hh_f, w_hh_r, xg, h_buf, ctr, out);
}

// Round 5
// 821.213 us; speedup vs baseline: 2.2247x; 2.2247x over previous
//
#include <hip/hip_runtime.h>
#include <math.h>

// Problem constants
#define NBOX 512
#define BATCH 16
#define TT 32
#define FEAT 2048
#define NCLS 80
#define CTXD 1024
#define FCD 1024
#define HID 1024
#define IN_DIM 3152     // FEAT + NCLS + CTXD
#define G4 4096         // 4*HID

// ---------------------------------------------------------------------------
// Kernel 1: build x = concat([box_feats, boxes_ext[:,5:], ctx_rep], dim=1)
// ---------------------------------------------------------------------------
__global__ void build_x(const float* __restrict__ boxes_ext,
                        const float* __restrict__ box_feats,
                        const float* __restrict__ spatial_ctx,
                        const int* __restrict__ box_im_ids,
                        float* __restrict__ x)
{
    int idx = blockIdx.x * blockDim.x + threadIdx.x;
    const int total = NBOX * IN_DIM;
    for (; idx < total; idx += gridDim.x * blockDim.x) {
        int n = idx / IN_DIM;
        int k = idx - n * IN_DIM;
        float v;
        if (k < FEAT) {
            v = box_feats[n * FEAT + k];
        } else if (k < FEAT + NCLS) {
            v = boxes_ext[n * 85 + 5 + (k - FEAT)];
        } else {
            v = spatial_ctx[box_im_ids[n] * CTXD + (k - FEAT - NCLS)];
        }
        x[idx] = v;
    }
}

// ---------------------------------------------------------------------------
// Kernel 2: emb GEMM, K-split partials. 64x64 tile, 256 threads (4 waves),
// 4x4 micro-tile, BK=16. Grid (8,16,8). K chunks 400/352, both %16==0.
// ---------------------------------------------------------------------------
__global__ __launch_bounds__(256) void gemm_emb_p2(
    const float* __restrict__ A,   // x [512][3152]
    const float* __restrict__ Bm,  // w_fc [1024][3152]
    float* __restrict__ part)      // [8][512][1024]
{
    __shared__ float As[16][68];
    __shared__ float Bs[16][68];
    const int bm = blockIdx.x * 64;
    const int bn = blockIdx.y * 64;
    const int kz = blockIdx.z;
    const int kbeg = kz * 400;
    const int kend = (kz == 7) ? IN_DIM : (kbeg + 400);
    const int t = threadIdx.x;
    const int tx = t & 15;         // 0..15 col-quad
    const int ty = t >> 4;         // 0..15 row-quad
    const int lr = t >> 2;         // staging row 0..63
    const int lk = (t & 3) * 4;    // staging k offset
    float acc[4][4] = {};

    const float* ap = A  + (size_t)(bm + lr) * IN_DIM + kbeg + lk;
    const float* bp = Bm + (size_t)(bn + lr) * IN_DIM + kbeg + lk;
    float4 pa = *(const float4*)ap;
    float4 pb = *(const float4*)bp;

    for (int k0 = kbeg; k0 < kend; k0 += 16) {
        As[lk+0][lr] = pa.x; As[lk+1][lr] = pa.y; As[lk+2][lr] = pa.z; As[lk+3][lr] = pa.w;
        Bs[lk+0][lr] = pb.x; Bs[lk+1][lr] = pb.y; Bs[lk+2][lr] = pb.z; Bs[lk+3][lr] = pb.w;
        __syncthreads();
        if (k0 + 16 < kend) {
            pa = *(const float4*)(ap + (k0 + 16 - kbeg));
            pb = *(const float4*)(bp + (k0 + 16 - kbeg));
        }
#pragma unroll
        for (int k = 0; k < 16; ++k) {
            float4 a4 = *(const float4*)&As[k][ty * 4];
            float4 b4 = *(const float4*)&Bs[k][tx * 4];
            float av[4] = {a4.x, a4.y, a4.z, a4.w};
            float bv[4] = {b4.x, b4.y, b4.z, b4.w};
#pragma unroll
            for (int i = 0; i < 4; ++i)
#pragma unroll
                for (int j = 0; j < 4; ++j)
                    acc[i][j] = fmaf(av[i], bv[j], acc[i][j]);
        }
        __syncthreads();
    }
    float* Cp = part + (size_t)kz * (NBOX * FCD) + (size_t)(bm + ty * 4) * FCD + bn + tx * 4;
#pragma unroll
    for (int i = 0; i < 4; ++i) {
        float4 v = make_float4(acc[i][0], acc[i][1], acc[i][2], acc[i][3]);
        *(float4*)(Cp + (size_t)i * FCD) = v;
    }
}

// Reduce K-split partials + bias + relu -> emb (written into d_out region)
__global__ void reduce_emb(const float* __restrict__ part,
                           const float* __restrict__ bias,
                           float* __restrict__ emb)
{
    int i = blockIdx.x * blockDim.x + threadIdx.x;
    if (i >= NBOX * FCD) return;
    float s = 0.f;
#pragma unroll
    for (int z = 0; z < 8; ++z) s += part[(size_t)z * (NBOX * FCD) + i];
    s += bias[i & (FCD - 1)];
    emb[i] = fmaxf(s, 0.f);
}

// ---------------------------------------------------------------------------
// Kernel 3: xg = emb @ w_ih^T + b_ih + b_hh (both dirs), same 256-thr tile.
// Grid (8, 128): by>>6 = dir, (by&63)*64 = col tile. K = 1024.
// ---------------------------------------------------------------------------
__global__ __launch_bounds__(256) void gemm_xg_p2(
    const float* __restrict__ A,   // emb [512][1024]
    const float* __restrict__ Bf, const float* __restrict__ Br,
    const float* __restrict__ bif, const float* __restrict__ bhf,
    const float* __restrict__ bir, const float* __restrict__ bhr,
    float* __restrict__ xg)        // [2][512][4096]
{
    __shared__ float As[16][68];
    __shared__ float Bs[16][68];
    const int bm = blockIdx.x * 64;
    const int by = blockIdx.y;
    const int dir = by >> 6;
    const int bn = (by & 63) * 64;
    const float* Bm = dir ? Br : Bf;
    const float* b1 = dir ? bir : bif;
    const float* b2 = dir ? bhr : bhf;
    float* C = xg + ((size_t)dir << 21);
    const int t = threadIdx.x;
    const int tx = t & 15;
    const int ty = t >> 4;
    const int lr = t >> 2;
    const int lk = (t & 3) * 4;
    float acc[4][4] = {};

    const float* ap = A  + (size_t)(bm + lr) * FCD + lk;
    const float* bp = Bm + (size_t)(bn + lr) * FCD + lk;
    float4 pa = *(const float4*)ap;
    float4 pb = *(const float4*)bp;

    for (int k0 = 0; k0 < 1024; k0 += 16) {
        As[lk+0][lr] = pa.x; As[lk+1][lr] = pa.y; As[lk+2][lr] = pa.z; As[lk+3][lr] = pa.w;
        Bs[lk+0][lr] = pb.x; Bs[lk+1][lr] = pb.y; Bs[lk+2][lr] = pb.z; Bs[lk+3][lr] = pb.w;
        __syncthreads();
        if (k0 + 16 < 1024) {
            pa = *(const float4*)(ap + k0 + 16);
            pb = *(const float4*)(bp + k0 + 16);
        }
#pragma unroll
        for (int k = 0; k < 16; ++k) {
            float4 a4 = *(const float4*)&As[k][ty * 4];
            float4 b4 = *(const float4*)&Bs[k][tx * 4];
            float av[4] = {a4.x, a4.y, a4.z, a4.w};
            float bv[4] = {b4.x, b4.y, b4.z, b4.w};
#pragma unroll
            for (int i = 0; i < 4; ++i)
#pragma unroll
                for (int j = 0; j < 4; ++j)
                    acc[i][j] = fmaf(av[i], bv[j], acc[i][j]);
        }
        __syncthreads();
    }
    const int col = bn + tx * 4;
    float4 b1v = *(const float4*)&b1[col];
    float4 b2v = *(const float4*)&b2[col];
#pragma unroll
    for (int i = 0; i < 4; ++i) {
        float4 v;
        v.x = acc[i][0] + b1v.x + b2v.x;
        v.y = acc[i][1] + b1v.y + b2v.y;
        v.z = acc[i][2] + b1v.z + b2v.z;
        v.w = acc[i][3] + b1v.w + b2v.w;
        *(float4*)(C + (size_t)(bm + ty * 4 + i) * G4 + col) = v;
    }
}

// ---------------------------------------------------------------------------
// Kernel 4: pack w_hh into per-step-block contiguous slices:
//   wpk[blk][k][32] fp32, blk = dir*128 + hb/8, col c: gate g=c&3, jl=c>>2,
//   source row = g*1024 + hb + jl. 128 KB per block, contiguous -> the step
//   kernel streams its own slice with zero line waste (fixes round-3's 2x
//   line waste + 4096-stride scatter that made each step ~26 us).
// ---------------------------------------------------------------------------
__global__ __launch_bounds__(256) void pack_whh(const float* __restrict__ wf,
                                                const float* __restrict__ wr,
                                                float* __restrict__ wpk)
{
    const int blk = blockIdx.x;          // 0..255
    const int dir = blk >> 7;
    const int hb  = (blk & 127) * 8;
    const float* src = dir ? wr : wf;
    const int t  = threadIdx.x;
    const int kq = t >> 5;               // 0..7 (128-k chunk)
    const int c  = t & 31;               // block-local col
    const int row = (c & 3) * 1024 + hb + (c >> 2);
    const float* sp = src + (size_t)row * 1024 + kq * 128;
    float* dp = wpk + (size_t)blk * 32768 + (size_t)(kq * 128) * 32 + c;
    for (int k2 = 0; k2 < 128; ++k2)
        dp[(size_t)k2 * 32] = sp[k2];
}

// ---------------------------------------------------------------------------
// Kernel 5: one LSTM timestep, both dirs. Launch-per-step (driver handles
// device coherence; round-4 measured that per-step software barriers +
// agent fences cost 2x a kernel launch). 256 blocks x 512 threads.
// Block (dir, hb) owns 8 hidden units x 4 gates = 32 cols; wave (jp,bg) does
// an 8col x 8batch outer product with lane-sliced k, then a shuffle-halving
// reduction (math identical to round-4's kernel, which passed).
// Weights stream from the packed contiguous slice; no LDS at all.
// ---------------------------------------------------------------------------
__global__ __launch_bounds__(512) void lstm_step_v5(
    const float* __restrict__ wpk,   // [256][1024][32] packed
    const float* __restrict__ xg,    // [2][512][4096]
    const float* __restrict__ hin,   // [2][1024][16] (phase-resolved)
    float* __restrict__ hout,        // [2][1024][16]
    float* __restrict__ c_g,         // [2][1024][16]
    float* __restrict__ hsum_g,      // [2][1024][16]
    int step)
{
    const int blk = blockIdx.x;
    const int dir = blk >> 7;
    const int hb  = (blk & 127) * 8;
    const int t   = threadIdx.x;
    const int lane = t & 63;
    const int wv   = t >> 6;        // wave 0..7
    const int jp   = wv >> 1;       // col-octet 0..3 (cols jp*8..+8)
    const int bg   = wv & 1;        // batch half

    const float* hrd = hin + dir * 16384;
    const float* wq  = wpk + (size_t)blk * 32768 + jp * 8;
    const float* xgd = xg + ((size_t)dir << 21);

    const int jl = lane >> 5;          // 0/1
    const int gg = (lane >> 3) & 3;    // gate id; gg==0 lanes own epilogue
    const int bb = lane & 7;
    const int j  = hb + jp * 2 + jl;   // global hidden index
    const int b  = bg * 8 + bb;        // batch

    const int tstep = dir ? (31 - step) : step;
    const int n = b * 32 + tstep;
    const float* xp = xgd + (size_t)n * G4 + j;
    float x0 = xp[0], x1 = xp[1024], x2 = xp[2048], x3 = xp[3072];

    float acc[64];
#pragma unroll
    for (int a = 0; a < 64; ++a) acc[a] = 0.f;

    // prime h loads for first 8 k-iterations (k = i*64 + lane)
    float4 hb0[8], hb1[8];
#pragma unroll
    for (int i = 0; i < 8; ++i) {
        const float4* hp = (const float4*)(hrd + (i * 64 + lane) * 16 + bg * 8);
        hb0[i] = hp[0]; hb1[i] = hp[1];
    }
#pragma unroll
    for (int i = 0; i < 16; ++i) {
        const int k = i * 64 + lane;
        const float4* wp = (const float4*)(wq + (size_t)k * 32);
        float4 w0 = wp[0];
        float4 w1 = wp[1];
        float4 h0 = hb0[i & 7], h1 = hb1[i & 7];
        if (i < 8) {   // rolling prefetch of iterations 8..15
            const float4* hp = (const float4*)(hrd + ((i + 8) * 64 + lane) * 16 + bg * 8);
            hb0[i & 7] = hp[0]; hb1[i & 7] = hp[1];
        }
        float wr[8] = {w0.x, w0.y, w0.z, w0.w, w1.x, w1.y, w1.z, w1.w};
        float hr[8] = {h0.x, h0.y, h0.z, h0.w, h1.x, h1.y, h1.z, h1.w};
#pragma unroll
        for (int cc = 0; cc < 8; ++cc)
#pragma unroll
            for (int b2 = 0; b2 < 8; ++b2)
                acc[cc * 8 + b2] = fmaf(wr[cc], hr[b2], acc[cc * 8 + b2]);
    }

    // ---- shuffle-halving reduction across 64 k-slice lanes (round-4 proven).
    // After all stages lane L holds slot L = (cc = L>>3, bb = L&7).
#pragma unroll
    for (int i2 = 0; i2 < 32; ++i2) {
        float ka = acc[i2], kb = acc[i2 + 32];
        float ta = __shfl_xor(ka, 32), tb = __shfl_xor(kb, 32);
        acc[i2] = (lane & 32) ? (kb + tb) : (ka + ta);
    }
#pragma unroll
    for (int i2 = 0; i2 < 16; ++i2) {
        float ka = acc[i2], kb = acc[i2 + 16];
        float ta = __shfl_xor(ka, 16), tb = __shfl_xor(kb, 16);
        acc[i2] = (lane & 16) ? (kb + tb) : (ka + ta);
    }
#pragma unroll
    for (int i2 = 0; i2 < 8; ++i2) {
        float ka = acc[i2], kb = acc[i2 + 8];
        float ta = __shfl_xor(ka, 8), tb = __shfl_xor(kb, 8);
        acc[i2] = (lane & 8) ? (kb + tb) : (ka + ta);
    }
#pragma unroll
    for (int i2 = 0; i2 < 4; ++i2) {
        float ka = acc[i2], kb = acc[i2 + 4];
        float ta = __shfl_xor(ka, 4), tb = __shfl_xor(kb, 4);
        acc[i2] = (lane & 4) ? (kb + tb) : (ka + ta);
    }
#pragma unroll
    for (int i2 = 0; i2 < 2; ++i2) {
        float ka = acc[i2], kb = acc[i2 + 2];
        float ta = __shfl_xor(ka, 2), tb = __shfl_xor(kb, 2);
        acc[i2] = (lane & 2) ? (kb + tb) : (ka + ta);
    }
    {
        float ka = acc[0], kb = acc[1];
        float ta = __shfl_xor(ka, 1), tb = __shfl_xor(kb, 1);
        acc[0] = (lane & 1) ? (kb + tb) : (ka + ta);
    }
    // gate gather: gg==0 lane pulls f/g/o partners from lanes +8/+16/+24
    float gv  = acc[0];
    float fv  = __shfl_xor(gv, 8);
    float gv2 = __shfl_xor(gv, 16);
    float ov  = __shfl_xor(gv, 24);

    if (gg == 0) {
        const int idx = dir * 16384 + j * 16 + b;
        float pi = gv + x0, pf = fv + x1, pg = gv2 + x2, po = ov + x3;
        float co = c_g[idx];
        float si = 1.f / (1.f + __expf(-pi));
        float sf = 1.f / (1.f + __expf(-pf));
        float so = 1.f / (1.f + __expf(-po));
        float cn = sf * co + si * tanhf(pg);
        float hn = so * tanhf(cn);
        c_g[idx] = cn;
        hout[idx] = hn;
        hsum_g[idx] += hn;
    }
}

// ---------------------------------------------------------------------------
// Kernel 6: object_context = hsum / T, reordered to [b][dir*H + j]
// ---------------------------------------------------------------------------
__global__ void finalize_ctx(const float* __restrict__ hsum, float* __restrict__ out)
{
    int i = blockIdx.x * blockDim.x + threadIdx.x;   // 32768
    if (i >= BATCH * 2 * HID) return;
    int b = i >> 11;
    int dir = (i >> 10) & 1;
    int j = i & 1023;
    out[i] = hsum[(dir << 14) + (j << 4) + b] * (1.0f / TT);
}

// ---------------------------------------------------------------------------
// Workspace plan (floats), total ~50.9 MB (round-3 proven size):
//   region A (8,388,608 = 32 MB), time-shared:
//     phase 1: x @0 (1,613,824), part @1,613,824 (4,194,304)
//     phase 2 (after reduce_emb): wpk = A  (256*1024*32 fp32 = 32 MB)
//   xg    @ 8,388,608  (4,194,304)
//   h_buf @ 12,582,912 (2 phases x 32,768)
//   c_g   @ 12,648,448 (32,768)
//   hsum  @ 12,681,216 (32,768)
// ---------------------------------------------------------------------------
extern "C" void kernel_launch(void* const* d_in, const int* in_sizes, int n_in,
                              void* d_out, int out_size, void* d_ws, size_t ws_size,
                              hipStream_t stream)
{
    const float* boxes_ext   = (const float*)d_in[0];
    const float* box_feats   = (const float*)d_in[1];
    const float* spatial_ctx = (const float*)d_in[2];
    const int*   box_im_ids  = (const int*)d_in[4];
    const float* w_fc   = (const float*)d_in[5];
    const float* b_fc   = (const float*)d_in[6];
    const float* w_ih_f = (const float*)d_in[7];
    const float* w_hh_f = (const float*)d_in[8];
    const float* b_ih_f = (const float*)d_in[9];
    const float* b_hh_f = (const float*)d_in[10];
    const float* w_ih_r = (const float*)d_in[11];
    const float* w_hh_r = (const float*)d_in[12];
    const float* b_ih_r = (const float*)d_in[13];
    const float* b_hh_r = (const float*)d_in[14];

    float* ws    = (float*)d_ws;
    float* x     = ws;                  // phase-1 of region A
    float* part  = ws + 1613824;        // phase-1 of region A
    float* wpk   = ws;                  // phase-2 of region A (32 MB)
    float* xg    = ws + 8388608;
    float* h_buf = ws + 12582912;       // 2 phases x 32768
    float* c_g   = ws + 12648448;
    float* hsum  = ws + 12681216;

    float* out = (float*)d_out;
    float* emb = out + 32768;           // second output region, also LSTM input

    // zero h phase-0/1, c, hsum (contiguous: 65536 + 32768 + 32768 floats)
    hipMemsetAsync(h_buf, 0, (size_t)(65536 + 32768 + 32768) * sizeof(float), stream);

    build_x<<<2048, 256, 0, stream>>>(boxes_ext, box_feats, spatial_ctx, box_im_ids, x);
    gemm_emb_p2<<<dim3(8, 16, 8), 256, 0, stream>>>(x, w_fc, part);
    reduce_emb<<<2048, 256, 0, stream>>>(part, b_fc, emb);
    // region A (x, part) is now dead -> safe to overwrite with packed weights
    pack_whh<<<256, 256, 0, stream>>>(w_hh_f, w_hh_r, wpk);
    gemm_xg_p2<<<dim3(8, 128), 256, 0, stream>>>(emb, w_ih_f, w_ih_r,
                                                 b_ih_f, b_hh_f, b_ih_r, b_hh_r, xg);
    for (int s = 0; s < TT; ++s) {
        float* hin  = h_buf + (s & 1) * 32768;
        float* hout = h_buf + ((s + 1) & 1) * 32768;
        lstm_step_v5<<<256, 512, 0, stream>>>(wpk, xg, hin, hout, c_g, hsum, s);
    }
    finalize_ctx<<<128, 256, 0, stream>>>(hsum, out);
}